// Round 4
// baseline (3853.997 us; speedup 1.0000x reference)
//
#include <hip/hip_runtime.h>
#include <hip/hip_bf16.h>
#include <math.h>

// Problem constants (fixed by the reference)
#define B_SZ 2
#define L_SEQ 4096
#define D_MODEL 1024
#define D_INNER 2048
#define D_STATE 64
#define DT_RANK 128
#define BL (B_SZ * L_SEQ)          // 8192 rows

// ---------------------------------------------------------------------------
// fp32 GEMM: C = act( A * B^T [+ bias] )
// A: M x K row-major (lda), B: N x K row-major (ldb)
// ct=0: C[m][n], ldc = n-stride.  ct=1: C^T[n][m], ldc = m-stride.
// act: 0 = none, 1 = softplus(+bias), 2 = silu
// Tile 128x128, BK=16, 256 threads, 8x8 per thread.
// ---------------------------------------------------------------------------
#define BM 128
#define BN 128
#define BK 16

__global__ __launch_bounds__(256) void gemm_abt(
    const float* __restrict__ A, int lda,
    const float* __restrict__ B, int ldb,
    float* __restrict__ C, int ldc,
    int K,
    const float* __restrict__ bias, int act, int ct)
{
    __shared__ float As[BK][BM + 4];
    __shared__ float Bs[BK][BN + 4];

    const int tid = threadIdx.x;
    const int bm = blockIdx.y * BM;
    const int bn = blockIdx.x * BN;
    const int tx = tid & 15;
    const int ty = tid >> 4;

    const int lr = tid >> 1;           // 0..127
    const int lc = (tid & 1) * 8;      // 0 or 8

    const float* Ag = A + (size_t)(bm + lr) * lda + lc;
    const float* Bg = B + (size_t)(bn + lr) * ldb + lc;

    float acc[8][8];
#pragma unroll
    for (int i = 0; i < 8; ++i)
#pragma unroll
        for (int j = 0; j < 8; ++j) acc[i][j] = 0.f;

    for (int k0 = 0; k0 < K; k0 += BK) {
        float4 a0 = *(const float4*)(Ag);
        float4 a1 = *(const float4*)(Ag + 4);
        float4 b0 = *(const float4*)(Bg);
        float4 b1 = *(const float4*)(Bg + 4);
        __syncthreads();
        As[lc + 0][lr] = a0.x; As[lc + 1][lr] = a0.y;
        As[lc + 2][lr] = a0.z; As[lc + 3][lr] = a0.w;
        As[lc + 4][lr] = a1.x; As[lc + 5][lr] = a1.y;
        As[lc + 6][lr] = a1.z; As[lc + 7][lr] = a1.w;
        Bs[lc + 0][lr] = b0.x; Bs[lc + 1][lr] = b0.y;
        Bs[lc + 2][lr] = b0.z; Bs[lc + 3][lr] = b0.w;
        Bs[lc + 4][lr] = b1.x; Bs[lc + 5][lr] = b1.y;
        Bs[lc + 6][lr] = b1.z; Bs[lc + 7][lr] = b1.w;
        __syncthreads();

#pragma unroll
        for (int kk = 0; kk < BK; ++kk) {
            float a[8], b[8];
            *(float4*)(a + 0) = *(const float4*)&As[kk][ty * 8 + 0];
            *(float4*)(a + 4) = *(const float4*)&As[kk][ty * 8 + 4];
            *(float4*)(b + 0) = *(const float4*)&Bs[kk][tx * 8 + 0];
            *(float4*)(b + 4) = *(const float4*)&Bs[kk][tx * 8 + 4];
#pragma unroll
            for (int i = 0; i < 8; ++i)
#pragma unroll
                for (int j = 0; j < 8; ++j)
                    acc[i][j] = fmaf(a[i], b[j], acc[i][j]);
        }
        Ag += BK;
        Bg += BK;
    }

    if (ct == 0) {
#pragma unroll
        for (int i = 0; i < 8; ++i) {
            float* crow = C + (size_t)(bm + ty * 8 + i) * ldc + bn + tx * 8;
            float v[8];
#pragma unroll
            for (int j = 0; j < 8; ++j) v[j] = acc[i][j];
            if (act == 1) {
#pragma unroll
                for (int j = 0; j < 8; ++j) {
                    float t = v[j] + bias[bn + tx * 8 + j];
                    v[j] = (t > 20.f) ? t : log1pf(__expf(t));
                }
            } else if (act == 2) {
#pragma unroll
                for (int j = 0; j < 8; ++j) v[j] = v[j] / (1.f + __expf(-v[j]));
            }
            *(float4*)(crow + 0) = *(const float4*)(v + 0);
            *(float4*)(crow + 4) = *(const float4*)(v + 4);
        }
    } else {
        // transposed store: C^T[n][m], per-j columns are m-contiguous
#pragma unroll
        for (int j = 0; j < 8; ++j) {
            int n = bn + tx * 8 + j;
            float v[8];
#pragma unroll
            for (int i = 0; i < 8; ++i) v[i] = acc[i][j];
            if (act == 1) {
                float bb = bias[n];
#pragma unroll
                for (int i = 0; i < 8; ++i) {
                    float t = v[i] + bb;
                    v[i] = (t > 20.f) ? t : log1pf(__expf(t));
                }
            } else if (act == 2) {
#pragma unroll
                for (int i = 0; i < 8; ++i) v[i] = v[i] / (1.f + __expf(-v[i]));
            }
            float* crow = C + (size_t)n * ldc + bm + ty * 8;
            *(float4*)(crow + 0) = *(const float4*)(v + 0);
            *(float4*)(crow + 4) = *(const float4*)(v + 4);
        }
    }
}

// ---------------------------------------------------------------------------
// fp32 GEMM, A transposed in memory: C[m][n] = sum_k A_T[k][m] * B[n][k]
// A_T: K x M row-major (ldA = m-stride), B: N x K row-major. C row-major.
// ---------------------------------------------------------------------------
__global__ __launch_bounds__(256) void gemm_atbt(
    const float* __restrict__ AT, int ldA,
    const float* __restrict__ B, int ldb,
    float* __restrict__ C, int ldc,
    int K)
{
    __shared__ float As[BK][BM + 4];
    __shared__ float Bs[BK][BN + 4];

    const int tid = threadIdx.x;
    const int bm = blockIdx.y * BM;
    const int bn = blockIdx.x * BN;
    const int tx = tid & 15;
    const int ty = tid >> 4;

    // A staging: thread loads A_T[k0+kr][bm+mc8 .. +7]  (coalesced rows)
    const int kr = tid >> 4;            // 0..15
    const int mc8 = (tid & 15) * 8;     // 0,8,...,120
    // B staging: as in gemm_abt
    const int lr = tid >> 1;
    const int lc = (tid & 1) * 8;

    const float* Ag = AT + (size_t)kr * ldA + bm + mc8;
    const float* Bg = B + (size_t)(bn + lr) * ldb + lc;

    float acc[8][8];
#pragma unroll
    for (int i = 0; i < 8; ++i)
#pragma unroll
        for (int j = 0; j < 8; ++j) acc[i][j] = 0.f;

    for (int k0 = 0; k0 < K; k0 += BK) {
        float4 a0 = *(const float4*)(Ag);
        float4 a1 = *(const float4*)(Ag + 4);
        float4 b0 = *(const float4*)(Bg);
        float4 b1 = *(const float4*)(Bg + 4);
        __syncthreads();
        *(float4*)&As[kr][mc8 + 0] = a0;
        *(float4*)&As[kr][mc8 + 4] = a1;
        Bs[lc + 0][lr] = b0.x; Bs[lc + 1][lr] = b0.y;
        Bs[lc + 2][lr] = b0.z; Bs[lc + 3][lr] = b0.w;
        Bs[lc + 4][lr] = b1.x; Bs[lc + 5][lr] = b1.y;
        Bs[lc + 6][lr] = b1.z; Bs[lc + 7][lr] = b1.w;
        __syncthreads();

#pragma unroll
        for (int kk = 0; kk < BK; ++kk) {
            float a[8], b[8];
            *(float4*)(a + 0) = *(const float4*)&As[kk][ty * 8 + 0];
            *(float4*)(a + 4) = *(const float4*)&As[kk][ty * 8 + 4];
            *(float4*)(b + 0) = *(const float4*)&Bs[kk][tx * 8 + 0];
            *(float4*)(b + 4) = *(const float4*)&Bs[kk][tx * 8 + 4];
#pragma unroll
            for (int i = 0; i < 8; ++i)
#pragma unroll
                for (int j = 0; j < 8; ++j)
                    acc[i][j] = fmaf(a[i], b[j], acc[i][j]);
        }
        Ag += (size_t)BK * ldA;
        Bg += BK;
    }

#pragma unroll
    for (int i = 0; i < 8; ++i) {
        float* crow = C + (size_t)(bm + ty * 8 + i) * ldc + bn + tx * 8;
        *(float4*)(crow + 0) = *(const float4*)&acc[i][0];
        *(float4*)(crow + 4) = *(const float4*)&acc[i][4];
    }
}

// ---------------------------------------------------------------------------
// causal depthwise conv (k=4) + bias + silu on transposed layout.
// xT: [2048][8192] (m = b*4096 + l). Each thread: one d, 4 consecutive m.
// ---------------------------------------------------------------------------
__global__ __launch_bounds__(256) void conv_silu_kernel(
    const float* __restrict__ xT,
    const float* __restrict__ w,      // [2048][4]
    const float* __restrict__ bias,   // [2048]
    float* __restrict__ xcT)
{
    int gid = blockIdx.x * blockDim.x + threadIdx.x;  // 0 .. 2048*2048-1
    int d = gid >> 11;
    int c4 = gid & 2047;
    int m0 = c4 * 4;
    int l0 = m0 & (L_SEQ - 1);

    const float* row = xT + (size_t)d * BL;
    float4 v = *(const float4*)(row + m0);
    float4 p;
    if (l0 == 0) { p.x = p.y = p.z = p.w = 0.f; }
    else         { p = *(const float4*)(row + m0 - 4); }

    float4 wv = ((const float4*)w)[d];
    float bb = bias[d];
    float e[4];
    e[0] = bb + wv.x * p.y + wv.y * p.z + wv.z * p.w + wv.w * v.x;
    e[1] = bb + wv.x * p.z + wv.y * p.w + wv.z * v.x + wv.w * v.y;
    e[2] = bb + wv.x * p.w + wv.y * v.x + wv.z * v.y + wv.w * v.z;
    e[3] = bb + wv.x * v.x + wv.y * v.y + wv.z * v.z + wv.w * v.w;
#pragma unroll
    for (int t = 0; t < 4; ++t) e[t] = e[t] / (1.f + __expf(-e[t]));
    *(float4*)(xcT + (size_t)d * BL + m0) = *(const float4*)e;
}

// ---------------------------------------------------------------------------
// Chunked parallel selective scan, transposed activations.
// One block (16 waves) per (b,d); lane = state n; wave = 256-step chunk.
// Rows dtT/xcT/zT [d][b*4096..] staged to LDS with float4 coalesced loads.
// y written in place over silu(z) row (float4, lane 0).
// ---------------------------------------------------------------------------
#define SCAN_WAVES 16
#define CL (L_SEQ / SCAN_WAVES)   // 256

__global__ __launch_bounds__(1024, 8) void scan_kernel(
    const float* __restrict__ dtT,    // [2048][8192]
    const float* __restrict__ xcT,    // [2048][8192]
    const float* __restrict__ xdbl,   // [8192][256]  (B at +128, C at +192)
    float* __restrict__ zyT,          // [2048][8192]: silu(z) in, y out
    const float* __restrict__ A_log,  // [2048][64]
    const float* __restrict__ Dp)     // [2048]
{
    __shared__ __align__(16) float s_dt[L_SEQ];
    __shared__ __align__(16) float s_x[L_SEQ];
    __shared__ __align__(16) float s_z[L_SEQ];
    __shared__ float s_P[SCAN_WAVES][D_STATE];
    __shared__ float s_H[SCAN_WAVES][D_STATE];

    const int bd  = blockIdx.x;            // 0..4095
    const int b   = bd >> 11;
    const int d   = bd & (D_INNER - 1);
    const int tid = threadIdx.x;
    const int wid = tid >> 6;
    const int lane = tid & 63;

    const size_t rowbase = (size_t)d * BL + (size_t)b * L_SEQ;

    ((float4*)s_dt)[tid] = ((const float4*)(dtT + rowbase))[tid];
    ((float4*)s_x)[tid]  = ((const float4*)(xcT + rowbase))[tid];
    ((float4*)s_z)[tid]  = ((const float4*)(zyT + rowbase))[tid];

    const float An = -__expf(A_log[d * D_STATE + lane]);
    const float Dd = Dp[d];
    __syncthreads();

    // ---- pass 1: local chunk scan (P = prod a, H = scan from 0) ----
    const int l0 = wid * CL;
    const float* bc = xdbl + ((size_t)b * L_SEQ + l0) * 256 + DT_RANK + lane;
    float P = 1.f, H = 0.f;
#pragma unroll 4
    for (int l = 0; l < CL; ++l) {
        float dtv = s_dt[l0 + l];
        float a = __expf(dtv * An);
        H = fmaf(H, a, dtv * s_x[l0 + l] * bc[0]);
        P *= a;
        bc += 256;
    }
    s_P[wid][lane] = P;
    s_H[wid][lane] = H;
    __syncthreads();

    // ---- pass 2: compose prefixes -> h_start for this chunk ----
    float h = 0.f;
    for (int c = 0; c < wid; ++c)
        h = fmaf(h, s_P[c][lane], s_H[c][lane]);

    // ---- pass 3: recompute with y output, 4-step batches ----
    float* yp = zyT + rowbase + l0;
    bc = xdbl + ((size_t)b * L_SEQ + l0) * 256 + DT_RANK + lane;
    for (int t0 = 0; t0 < CL; t0 += 4) {
        float Bv[4], Cv[4];
#pragma unroll
        for (int t = 0; t < 4; ++t) {
            Bv[t] = bc[0];
            Cv[t] = bc[D_STATE];
            bc += 256;
        }
        float p[4], xv[4];
#pragma unroll
        for (int t = 0; t < 4; ++t) {
            float dtv = s_dt[l0 + t0 + t];
            xv[t] = s_x[l0 + t0 + t];
            float a = __expf(dtv * An);
            h = fmaf(h, a, dtv * xv[t] * Bv[t]);
            p[t] = h * Cv[t];
        }
#pragma unroll
        for (int t = 0; t < 4; ++t) {
            p[t] += __shfl_xor(p[t], 32);
            p[t] += __shfl_xor(p[t], 16);
            p[t] += __shfl_xor(p[t], 8);
            p[t] += __shfl_xor(p[t], 4);
            p[t] += __shfl_xor(p[t], 2);
            p[t] += __shfl_xor(p[t], 1);
        }
        if (lane == 0) {
            float4 y4;
            y4.x = fmaf(Dd, xv[0], p[0]) * s_z[l0 + t0 + 0];
            y4.y = fmaf(Dd, xv[1], p[1]) * s_z[l0 + t0 + 1];
            y4.z = fmaf(Dd, xv[2], p[2]) * s_z[l0 + t0 + 2];
            y4.w = fmaf(Dd, xv[3], p[3]) * s_z[l0 + t0 + 3];
            *(float4*)(yp + t0) = y4;
        }
    }
}

// ---------------------------------------------------------------------------
extern "C" void kernel_launch(void* const* d_in, const int* in_sizes, int n_in,
                              void* d_out, int out_size, void* d_ws, size_t ws_size,
                              hipStream_t stream)
{
    const float* hs        = (const float*)d_in[0];  // [2,4096,1024]
    const float* in_proj_w = (const float*)d_in[1];  // [4096,1024]
    const float* conv_w    = (const float*)d_in[2];  // [2048,1,4]
    const float* conv_b    = (const float*)d_in[3];  // [2048]
    const float* x_proj_w  = (const float*)d_in[4];  // [256,2048]
    const float* dt_proj_w = (const float*)d_in[5];  // [2048,128]
    const float* dt_proj_b = (const float*)d_in[6];  // [2048]
    const float* A_log     = (const float*)d_in[7];  // [2048,64]
    const float* Dp        = (const float*)d_in[8];  // [2048]
    const float* out_proj_w= (const float*)d_in[9];  // [1024,2048]
    float* out = (float*)d_out;                      // [2,4096,1024]

    // workspace (209.7 MB): all activation tensors stored TRANSPOSED [d][m]
    //   xT  [2048][8192] @ 0      : pre-conv x, reused for dtT
    //   zT  [2048][8192] @ 64 MB  : silu(z), y written in place
    //   xcT [2048][8192] @ 128 MB : post-conv x
    //   xdbl [8192][256] @ 192 MB : row-major (scan B/C reads are lane-coalesced)
    char* ws = (char*)d_ws;
    float* xT   = (float*)ws;
    float* zT   = (float*)(ws + (size_t)BL * D_INNER * 4);
    float* xcT  = (float*)(ws + (size_t)2 * BL * D_INNER * 4);
    float* xdbl = (float*)(ws + (size_t)3 * BL * D_INNER * 4);

    dim3 blk(256);

    // 1) xT = (hs @ in_proj_w[:2048]^T)^T     (transposed store)
    gemm_abt<<<dim3(D_INNER / BN, BL / BM), blk, 0, stream>>>(
        hs, D_MODEL, in_proj_w, D_MODEL, xT, BL, D_MODEL, nullptr, 0, 1);

    // 2) zT = silu(hs @ in_proj_w[2048:]^T)^T
    gemm_abt<<<dim3(D_INNER / BN, BL / BM), blk, 0, stream>>>(
        hs, D_MODEL, in_proj_w + (size_t)D_INNER * D_MODEL, D_MODEL,
        zT, BL, D_MODEL, nullptr, 2, 1);

    // 3) xcT = silu(conv(xT) + b)   (row-wise, coalesced)
    conv_silu_kernel<<<(D_INNER * (BL / 4)) / 256, blk, 0, stream>>>(
        xT, conv_w, conv_b, xcT);

    // 4) xdbl = xc @ x_proj_w^T   via A^T GEMM  (8192 x 256, K=2048)
    gemm_atbt<<<dim3(256 / BN, BL / BM), blk, 0, stream>>>(
        xcT, BL, x_proj_w, D_INNER, xdbl, 256, D_INNER);

    // 5) dtT = softplus(xdbl[:, :128] @ dt_proj_w^T + b)^T  -> reuse xT
    gemm_abt<<<dim3(D_INNER / BN, BL / BM), blk, 0, stream>>>(
        xdbl, 256, dt_proj_w, DT_RANK, xT, BL, DT_RANK, dt_proj_b, 1, 1);

    // 6) chunked parallel scan -> y in place over zT
    scan_kernel<<<B_SZ * D_INNER, dim3(1024), 0, stream>>>(
        xT, xcT, xdbl, zT, A_log, Dp);

    // 7) out = y @ out_proj_w^T   via A^T GEMM  (8192 x 1024, K=2048)
    gemm_atbt<<<dim3(D_MODEL / BN, BL / BM), blk, 0, stream>>>(
        zT, BL, out_proj_w, D_INNER, out, D_MODEL, D_INNER);
}

// Round 5
// 1679.749 us; speedup vs baseline: 2.2944x; 2.2944x over previous
//
#include <hip/hip_runtime.h>
#include <math.h>

// Problem constants (fixed by the reference)
#define B_SZ 2
#define L_SEQ 4096
#define D_MODEL 1024
#define D_INNER 2048
#define D_STATE 64
#define DT_RANK 128
#define BL (B_SZ * L_SEQ)          // 8192 tokens

#define AS1 __attribute__((address_space(1)))
#define AS3 __attribute__((address_space(3)))

typedef __attribute__((ext_vector_type(8))) short bf16x8_t;  // 8 bf16 = 4 VGPRs
typedef __attribute__((ext_vector_type(4))) float f32x4_t;

__device__ __forceinline__ unsigned short f2bf(float f) {
    unsigned int u = __float_as_uint(f);
    u = (u + 0x7FFFu + ((u >> 16) & 1u)) >> 16;   // RNE
    return (unsigned short)u;
}
__device__ __forceinline__ float bf2f(unsigned short h) {
    return __uint_as_float(((unsigned int)h) << 16);
}

// ---------------------------------------------------------------------------
// fp32 -> bf16 bulk convert (n4 = count of float4 groups)
// ---------------------------------------------------------------------------
__global__ __launch_bounds__(256) void cvt_f32_bf16(
    const float* __restrict__ in, unsigned short* __restrict__ out, int n4)
{
    int i = blockIdx.x * 256 + threadIdx.x;
    if (i >= n4) return;
    float4 v = ((const float4*)in)[i];
    ushort4 o;
    o.x = f2bf(v.x); o.y = f2bf(v.y); o.z = f2bf(v.z); o.w = f2bf(v.w);
    ((ushort4*)out)[i] = o;
}

// xdbl[:, :128] (fp32, row stride 256) -> packed bf16 [8192][128]
__global__ __launch_bounds__(256) void cvt_dtpart(
    const float* __restrict__ xdbl, unsigned short* __restrict__ out)
{
    int i = blockIdx.x * 256 + threadIdx.x;   // 0 .. 8192*32-1
    int m = i >> 5, c = i & 31;
    float4 v = *(const float4*)(xdbl + (size_t)m * 256 + c * 4);
    ushort4 o;
    o.x = f2bf(v.x); o.y = f2bf(v.y); o.z = f2bf(v.z); o.w = f2bf(v.w);
    ((ushort4*)(out))[(size_t)m * 32 + c] = o;
}

// ---------------------------------------------------------------------------
// bf16 MFMA GEMM: C[m][n] = act( sum_k A[m][k]*B[n][k] [+ bias[m]] )
// A: M x K bf16 row-major (lda), B: N x K bf16 row-major (ldb), C fp32 (ldc).
// act: 0 none, 1 softplus with bias indexed by ROW m, 2 silu.
// Tile 128x128, BK=32, 256 threads = 4 waves (2x2 of 64x64 per wave).
// m97 structure: global_load_lds width-16 staging, 2-barrier K-loop.
// ---------------------------------------------------------------------------
__global__ __launch_bounds__(256) void gemm_bf16(
    const unsigned short* __restrict__ A, int lda,
    const unsigned short* __restrict__ B, int ldb,
    float* __restrict__ C, int ldc, int K,
    const float* __restrict__ bias, int act)
{
    __shared__ unsigned short As[128 * 32];   // [row][k] linear, no pad
    __shared__ unsigned short Bs[128 * 32];

    const int tid = threadIdx.x;
    const int w = tid >> 6, lane = tid & 63;
    const int bm = blockIdx.y * 128, bn = blockIdx.x * 128;
    const int wm = (w & 1) * 64, wn = (w >> 1) * 64;

    f32x4_t acc[4][4];
#pragma unroll
    for (int i = 0; i < 4; ++i)
#pragma unroll
        for (int j = 0; j < 4; ++j) acc[i][j] = (f32x4_t){0.f, 0.f, 0.f, 0.f};

    // staging: wave w, issue s covers rows s*64 + w*16 + (lane>>2), cols (lane&3)*8..+7
    const int srow = lane >> 2;
    const int scol = (lane & 3) * 8;
    const unsigned short* Ag0 = A + (size_t)(bm + w * 16 + srow) * lda + scol;
    const unsigned short* Ag1 = A + (size_t)(bm + 64 + w * 16 + srow) * lda + scol;
    const unsigned short* Bg0 = B + (size_t)(bn + w * 16 + srow) * ldb + scol;
    const unsigned short* Bg1 = B + (size_t)(bn + 64 + w * 16 + srow) * ldb + scol;
    unsigned short* la0 = &As[(w * 16) * 32];        // wave-uniform LDS bases
    unsigned short* la1 = &As[(64 + w * 16) * 32];
    unsigned short* lb0 = &Bs[(w * 16) * 32];
    unsigned short* lb1 = &Bs[(64 + w * 16) * 32];

    const int fr = lane & 15;            // fragment free index
    const int fk = (lane >> 4) * 8;      // fragment k offset

    for (int k0 = 0; k0 < K; k0 += 32) {
        __syncthreads();   // previous iteration's ds_reads done
        __builtin_amdgcn_global_load_lds((const AS1 void*)(Ag0 + k0), (AS3 void*)la0, 16, 0, 0);
        __builtin_amdgcn_global_load_lds((const AS1 void*)(Ag1 + k0), (AS3 void*)la1, 16, 0, 0);
        __builtin_amdgcn_global_load_lds((const AS1 void*)(Bg0 + k0), (AS3 void*)lb0, 16, 0, 0);
        __builtin_amdgcn_global_load_lds((const AS1 void*)(Bg1 + k0), (AS3 void*)lb1, 16, 0, 0);
        __syncthreads();   // vmcnt(0) drained before barrier -> staging visible

        bf16x8_t af[4], bfr[4];
#pragma unroll
        for (int i = 0; i < 4; ++i)
            af[i] = *(const bf16x8_t*)&As[(wm + i * 16 + fr) * 32 + fk];
#pragma unroll
        for (int j = 0; j < 4; ++j)
            bfr[j] = *(const bf16x8_t*)&Bs[(wn + j * 16 + fr) * 32 + fk];
#pragma unroll
        for (int i = 0; i < 4; ++i)
#pragma unroll
            for (int j = 0; j < 4; ++j)
                acc[i][j] = __builtin_amdgcn_mfma_f32_16x16x32_bf16(
                    af[i], bfr[j], acc[i][j], 0, 0, 0);
    }

    // epilogue: C/D layout col=lane&15, row=(lane>>4)*4+reg  [m89/m91-verified]
    const int erow = (lane >> 4) * 4;
    const int ecol = lane & 15;
#pragma unroll
    for (int i = 0; i < 4; ++i) {
        int gr0 = bm + wm + i * 16 + erow;
#pragma unroll
        for (int j = 0; j < 4; ++j) {
            int gc = bn + wn + j * 16 + ecol;
#pragma unroll
            for (int r = 0; r < 4; ++r) {
                float v = acc[i][j][r];
                if (act == 1) {
                    float t = v + bias[gr0 + r];
                    v = (t > 20.f) ? t : log1pf(__expf(t));
                } else if (act == 2) {
                    v = v / (1.f + __expf(-v));
                }
                C[(size_t)(gr0 + r) * ldc + gc] = v;
            }
        }
    }
}

// ---------------------------------------------------------------------------
// causal depthwise conv (k=4) + bias + silu on [d][m] layout, bf16 output.
// ---------------------------------------------------------------------------
__global__ __launch_bounds__(256) void conv_silu_kernel(
    const float* __restrict__ xT,     // [2048][8192] fp32
    const float* __restrict__ w,      // [2048][4]
    const float* __restrict__ bias,   // [2048]
    unsigned short* __restrict__ xcT16) // [2048][8192] bf16
{
    int gid = blockIdx.x * blockDim.x + threadIdx.x;  // 0 .. 2048*2048-1
    int d = gid >> 11;
    int c4 = gid & 2047;
    int m0 = c4 * 4;
    int l0 = m0 & (L_SEQ - 1);

    const float* row = xT + (size_t)d * BL;
    float4 v = *(const float4*)(row + m0);
    float4 p;
    if (l0 == 0) { p.x = p.y = p.z = p.w = 0.f; }
    else         { p = *(const float4*)(row + m0 - 4); }

    float4 wv = ((const float4*)w)[d];
    float bb = bias[d];
    float e[4];
    e[0] = bb + wv.x * p.y + wv.y * p.z + wv.z * p.w + wv.w * v.x;
    e[1] = bb + wv.x * p.z + wv.y * p.w + wv.z * v.x + wv.w * v.y;
    e[2] = bb + wv.x * p.w + wv.y * v.x + wv.z * v.y + wv.w * v.z;
    e[3] = bb + wv.x * v.x + wv.y * v.y + wv.z * v.z + wv.w * v.w;
    ushort4 o;
    o.x = f2bf(e[0] / (1.f + __expf(-e[0])));
    o.y = f2bf(e[1] / (1.f + __expf(-e[1])));
    o.z = f2bf(e[2] / (1.f + __expf(-e[2])));
    o.w = f2bf(e[3] / (1.f + __expf(-e[3])));
    ((ushort4*)(xcT16 + (size_t)d * BL))[c4] = o;
}

// ---------------------------------------------------------------------------
// 32x32 tiled transposes (coalesced both sides)
// ---------------------------------------------------------------------------
__global__ __launch_bounds__(256) void transpose_f32_bf16(
    const float* __restrict__ in, int ldin,        // [R][ldin] fp32
    unsigned short* __restrict__ out, int ldout)   // [C][ldout] bf16
{
    __shared__ float tl[32][33];
    int r0 = blockIdx.y * 32, c0 = blockIdx.x * 32;
    int tx = threadIdx.x & 31, ty = threadIdx.x >> 5;  // ty 0..7
#pragma unroll
    for (int k = 0; k < 4; ++k)
        tl[ty + 8 * k][tx] = in[(size_t)(r0 + ty + 8 * k) * ldin + c0 + tx];
    __syncthreads();
#pragma unroll
    for (int k = 0; k < 4; ++k)
        out[(size_t)(c0 + ty + 8 * k) * ldout + r0 + tx] = f2bf(tl[tx][ty + 8 * k]);
}

__global__ __launch_bounds__(256) void transpose_bf16(
    const unsigned short* __restrict__ in, int ldin,
    unsigned short* __restrict__ out, int ldout)
{
    __shared__ unsigned short tl[32][33];
    int r0 = blockIdx.y * 32, c0 = blockIdx.x * 32;
    int tx = threadIdx.x & 31, ty = threadIdx.x >> 5;
#pragma unroll
    for (int k = 0; k < 4; ++k)
        tl[ty + 8 * k][tx] = in[(size_t)(r0 + ty + 8 * k) * ldin + c0 + tx];
    __syncthreads();
#pragma unroll
    for (int k = 0; k < 4; ++k)
        out[(size_t)(c0 + ty + 8 * k) * ldout + r0 + tx] = tl[tx][ty + 8 * k];
}

// ---------------------------------------------------------------------------
// Chunked parallel selective scan (structure identical to R4; x is bf16 now).
// ---------------------------------------------------------------------------
#define SCAN_WAVES 16
#define CL (L_SEQ / SCAN_WAVES)   // 256

__global__ __launch_bounds__(1024, 8) void scan_kernel(
    const float* __restrict__ dtT,           // [2048][8192] fp32
    const unsigned short* __restrict__ xcT16,// [2048][8192] bf16
    const float* __restrict__ xdbl,          // [8192][256] fp32 (B at +128, C at +192)
    float* __restrict__ zyT,                 // [2048][8192]: silu(z) in, y out
    const float* __restrict__ A_log,         // [2048][64]
    const float* __restrict__ Dp)            // [2048]
{
    __shared__ __align__(16) float s_dt[L_SEQ];
    __shared__ __align__(16) float s_x[L_SEQ];
    __shared__ __align__(16) float s_z[L_SEQ];
    __shared__ float s_P[SCAN_WAVES][D_STATE];
    __shared__ float s_H[SCAN_WAVES][D_STATE];

    const int bd  = blockIdx.x;            // 0..4095
    const int b   = bd >> 11;
    const int d   = bd & (D_INNER - 1);
    const int tid = threadIdx.x;
    const int wid = tid >> 6;
    const int lane = tid & 63;

    const size_t rowbase = (size_t)d * BL + (size_t)b * L_SEQ;

    ((float4*)s_dt)[tid] = ((const float4*)(dtT + rowbase))[tid];
    {
        ushort4 xr = ((const ushort4*)(xcT16 + rowbase))[tid];
        float4 xf;
        xf.x = bf2f(xr.x); xf.y = bf2f(xr.y); xf.z = bf2f(xr.z); xf.w = bf2f(xr.w);
        ((float4*)s_x)[tid] = xf;
    }
    ((float4*)s_z)[tid] = ((const float4*)(zyT + rowbase))[tid];

    const float An = -__expf(A_log[d * D_STATE + lane]);
    const float Dd = Dp[d];
    __syncthreads();

    // ---- pass 1: local chunk scan ----
    const int l0 = wid * CL;
    const float* bc = xdbl + ((size_t)b * L_SEQ + l0) * 256 + DT_RANK + lane;
    float P = 1.f, H = 0.f;
#pragma unroll 4
    for (int l = 0; l < CL; ++l) {
        float dtv = s_dt[l0 + l];
        float a = __expf(dtv * An);
        H = fmaf(H, a, dtv * s_x[l0 + l] * bc[0]);
        P *= a;
        bc += 256;
    }
    s_P[wid][lane] = P;
    s_H[wid][lane] = H;
    __syncthreads();

    // ---- pass 2: compose prefixes -> h_start ----
    float h = 0.f;
    for (int c = 0; c < wid; ++c)
        h = fmaf(h, s_P[c][lane], s_H[c][lane]);

    // ---- pass 3: recompute with y output ----
    float* yp = zyT + rowbase + l0;
    bc = xdbl + ((size_t)b * L_SEQ + l0) * 256 + DT_RANK + lane;
    for (int t0 = 0; t0 < CL; t0 += 4) {
        float Bv[4], Cv[4];
#pragma unroll
        for (int t = 0; t < 4; ++t) {
            Bv[t] = bc[0];
            Cv[t] = bc[D_STATE];
            bc += 256;
        }
        float p[4], xv[4];
#pragma unroll
        for (int t = 0; t < 4; ++t) {
            float dtv = s_dt[l0 + t0 + t];
            xv[t] = s_x[l0 + t0 + t];
            float a = __expf(dtv * An);
            h = fmaf(h, a, dtv * xv[t] * Bv[t]);
            p[t] = h * Cv[t];
        }
#pragma unroll
        for (int t = 0; t < 4; ++t) {
            p[t] += __shfl_xor(p[t], 32);
            p[t] += __shfl_xor(p[t], 16);
            p[t] += __shfl_xor(p[t], 8);
            p[t] += __shfl_xor(p[t], 4);
            p[t] += __shfl_xor(p[t], 2);
            p[t] += __shfl_xor(p[t], 1);
        }
        if (lane == 0) {
            float4 y4;
            y4.x = fmaf(Dd, xv[0], p[0]) * s_z[l0 + t0 + 0];
            y4.y = fmaf(Dd, xv[1], p[1]) * s_z[l0 + t0 + 1];
            y4.z = fmaf(Dd, xv[2], p[2]) * s_z[l0 + t0 + 2];
            y4.w = fmaf(Dd, xv[3], p[3]) * s_z[l0 + t0 + 3];
            *(float4*)(yp + t0) = y4;
        }
    }
}

// ---------------------------------------------------------------------------
extern "C" void kernel_launch(void* const* d_in, const int* in_sizes, int n_in,
                              void* d_out, int out_size, void* d_ws, size_t ws_size,
                              hipStream_t stream)
{
    const float* hs        = (const float*)d_in[0];  // [8192][1024]
    const float* in_proj_w = (const float*)d_in[1];  // [4096][1024]
    const float* conv_w    = (const float*)d_in[2];  // [2048][4]
    const float* conv_b    = (const float*)d_in[3];  // [2048]
    const float* x_proj_w  = (const float*)d_in[4];  // [256][2048]
    const float* dt_proj_w = (const float*)d_in[5];  // [2048][128]
    const float* dt_proj_b = (const float*)d_in[6];  // [2048]
    const float* A_log     = (const float*)d_in[7];  // [2048][64]
    const float* Dp        = (const float*)d_in[8];  // [2048]
    const float* out_proj_w= (const float*)d_in[9];  // [1024][2048]
    float* out = (float*)d_out;                      // [8192][1024]

    // workspace map (MiB offsets; peak 176 MiB < proven 200 MiB):
    //  S0 @0   : xT fp32 (64)  -> xc16 bf16 (32) @0  -> dtT fp32 (64) @0
    //  S1 @64  : zT fp32 (64)  (scan writes y in place)
    //  S2 @128 : W1_16 (8)@128 + hs16 (16)@136  -> xcT16 bf16 (32)@128 -> y16 (32)@128
    //  tail@160: xdbl fp32 (8)@160, xdbl16 (2)@168, Wx16 (1)@170,
    //            Wdt16 (.5)@171, Wo16 (4)@172   (end 176)
    char* ws = (char*)d_ws;
    const size_t MiB = 1024 * 1024;
    float*          xT    = (float*)(ws);
    unsigned short* xc16  = (unsigned short*)(ws);
    float*          dtT   = (float*)(ws);
    float*          zT    = (float*)(ws + 64 * MiB);
    unsigned short* W1_16 = (unsigned short*)(ws + 128 * MiB);
    unsigned short* hs16  = (unsigned short*)(ws + 136 * MiB);
    unsigned short* xcT16 = (unsigned short*)(ws + 128 * MiB);
    unsigned short* y16   = (unsigned short*)(ws + 128 * MiB);
    float*          xdbl  = (float*)(ws + 160 * MiB);
    unsigned short* xdbl16= (unsigned short*)(ws + 168 * MiB);
    unsigned short* Wx16  = (unsigned short*)(ws + 170 * MiB);
    unsigned short* Wdt16 = (unsigned short*)(ws + 171 * MiB);
    unsigned short* Wo16  = (unsigned short*)(ws + 172 * MiB);

    dim3 blk(256);

    // bf16 conversions
    cvt_f32_bf16<<<8192, blk, 0, stream>>>(hs, hs16, 2097152);
    cvt_f32_bf16<<<4096, blk, 0, stream>>>(in_proj_w, W1_16, 1048576);
    cvt_f32_bf16<<<512, blk, 0, stream>>>(x_proj_w, Wx16, 131072);
    cvt_f32_bf16<<<256, blk, 0, stream>>>(dt_proj_w, Wdt16, 65536);
    cvt_f32_bf16<<<2048, blk, 0, stream>>>(out_proj_w, Wo16, 524288);

    // 1) xT[d][m] = W1x . hs^T   (M=2048, N=8192, K=1024)
    gemm_bf16<<<dim3(64, 16), blk, 0, stream>>>(
        W1_16, D_MODEL, hs16, D_MODEL, xT, BL, D_MODEL, nullptr, 0);

    // 2) zT[d][m] = silu(W1z . hs^T)
    gemm_bf16<<<dim3(64, 16), blk, 0, stream>>>(
        W1_16 + (size_t)D_INNER * D_MODEL, D_MODEL, hs16, D_MODEL,
        zT, BL, D_MODEL, nullptr, 2);

    // 3) xcT16 = bf16(silu(conv(xT) + b))
    conv_silu_kernel<<<(D_INNER * (BL / 4)) / 256, blk, 0, stream>>>(
        xT, conv_w, conv_b, xcT16);

    // 4) xc16[m][d] = transpose(xcT16)
    transpose_bf16<<<dim3(BL / 32, D_INNER / 32), blk, 0, stream>>>(
        xcT16, BL, xc16, D_INNER);

    // 5) xdbl[m][256] = xc . x_proj^T   (M=8192, N=256, K=2048)
    gemm_bf16<<<dim3(2, 64), blk, 0, stream>>>(
        xc16, D_INNER, Wx16, D_INNER, xdbl, 256, D_INNER, nullptr, 0);

    // 6) xdbl16 = bf16(xdbl[:, :128])
    cvt_dtpart<<<1024, blk, 0, stream>>>(xdbl, xdbl16);

    // 7) dtT[d][m] = softplus(Wdt . xdbl_dt^T + b[d])  (M=2048, N=8192, K=128)
    gemm_bf16<<<dim3(64, 16), blk, 0, stream>>>(
        Wdt16, DT_RANK, xdbl16, DT_RANK, dtT, BL, DT_RANK, dt_proj_b, 1);

    // 8) chunked scan -> y in place over zT
    scan_kernel<<<B_SZ * D_INNER, dim3(1024), 0, stream>>>(
        dtT, xcT16, xdbl, zT, A_log, Dp);

    // 9) y16[m][d] = bf16(transpose(zT))
    transpose_f32_bf16<<<dim3(BL / 32, D_INNER / 32), blk, 0, stream>>>(
        zT, BL, y16, D_INNER);

    // 10) out = y . out_proj^T   (M=8192, N=1024, K=2048)
    gemm_bf16<<<dim3(8, 64), blk, 0, stream>>>(
        y16, D_INNER, Wo16, D_INNER, out, D_MODEL, D_INNER, nullptr, 0);
}

// Round 7
// 1123.008 us; speedup vs baseline: 3.4319x; 1.4958x over previous
//
#include <hip/hip_runtime.h>
#include <math.h>

// Problem constants (fixed by the reference)
#define B_SZ 2
#define L_SEQ 4096
#define D_MODEL 1024
#define D_INNER 2048
#define D_STATE 64
#define DT_RANK 128
#define BL (B_SZ * L_SEQ)          // 8192 tokens

#define AS1 __attribute__((address_space(1)))
#define AS3 __attribute__((address_space(3)))

typedef __attribute__((ext_vector_type(8))) short bf16x8_t;  // 8 bf16 = 4 VGPRs
typedef __attribute__((ext_vector_type(4))) float f32x4_t;

__device__ __forceinline__ unsigned short f2bf(float f) {
    unsigned int u = __float_as_uint(f);
    u = (u + 0x7FFFu + ((u >> 16) & 1u)) >> 16;   // RNE
    return (unsigned short)u;
}
__device__ __forceinline__ float bf2f(unsigned short h) {
    return __uint_as_float(((unsigned int)h) << 16);
}

// ---------------------------------------------------------------------------
// fp32 -> bf16 bulk convert (n4 = count of float4 groups)
// ---------------------------------------------------------------------------
__global__ __launch_bounds__(256) void cvt_f32_bf16(
    const float* __restrict__ in, unsigned short* __restrict__ out, int n4)
{
    int i = blockIdx.x * 256 + threadIdx.x;
    if (i >= n4) return;
    float4 v = ((const float4*)in)[i];
    ushort4 o;
    o.x = f2bf(v.x); o.y = f2bf(v.y); o.z = f2bf(v.z); o.w = f2bf(v.w);
    ((ushort4*)out)[i] = o;
}

// xdbl[:, :128] (fp32, row stride 256) -> packed bf16 [8192][128]
__global__ __launch_bounds__(256) void cvt_dtpart(
    const float* __restrict__ xdbl, unsigned short* __restrict__ out)
{
    int i = blockIdx.x * 256 + threadIdx.x;   // 0 .. 8192*32-1
    int m = i >> 5, c = i & 31;
    float4 v = *(const float4*)(xdbl + (size_t)m * 256 + c * 4);
    ushort4 o;
    o.x = f2bf(v.x); o.y = f2bf(v.y); o.z = f2bf(v.z); o.w = f2bf(v.w);
    ((ushort4*)(out))[(size_t)m * 32 + c] = o;
}

// ---------------------------------------------------------------------------
// bf16 MFMA GEMM: C[m][n] = act( sum_k A[m][k]*B[n][k] [+ bias[m]] )
// A: M x K bf16 row-major (lda), B: N x K bf16 row-major (ldb), C fp32 (ldc).
// act: 0 none, 1 softplus with bias indexed by ROW m, 2 silu.
// Tile 128x128, BK=32, 256 threads = 4 waves (2x2 of 64x64 per wave).
// ---------------------------------------------------------------------------
__global__ __launch_bounds__(256) void gemm_bf16(
    const unsigned short* __restrict__ A, int lda,
    const unsigned short* __restrict__ B, int ldb,
    float* __restrict__ C, int ldc, int K,
    const float* __restrict__ bias, int act)
{
    __shared__ unsigned short As[128 * 32];   // [row][k] linear, no pad
    __shared__ unsigned short Bs[128 * 32];

    const int tid = threadIdx.x;
    const int w = tid >> 6, lane = tid & 63;
    const int bm = blockIdx.y * 128, bn = blockIdx.x * 128;
    const int wm = (w & 1) * 64, wn = (w >> 1) * 64;

    f32x4_t acc[4][4];
#pragma unroll
    for (int i = 0; i < 4; ++i)
#pragma unroll
        for (int j = 0; j < 4; ++j) acc[i][j] = (f32x4_t){0.f, 0.f, 0.f, 0.f};

    const int srow = lane >> 2;
    const int scol = (lane & 3) * 8;
    const unsigned short* Ag0 = A + (size_t)(bm + w * 16 + srow) * lda + scol;
    const unsigned short* Ag1 = A + (size_t)(bm + 64 + w * 16 + srow) * lda + scol;
    const unsigned short* Bg0 = B + (size_t)(bn + w * 16 + srow) * ldb + scol;
    const unsigned short* Bg1 = B + (size_t)(bn + 64 + w * 16 + srow) * ldb + scol;
    unsigned short* la0 = &As[(w * 16) * 32];
    unsigned short* la1 = &As[(64 + w * 16) * 32];
    unsigned short* lb0 = &Bs[(w * 16) * 32];
    unsigned short* lb1 = &Bs[(64 + w * 16) * 32];

    const int fr = lane & 15;
    const int fk = (lane >> 4) * 8;

    for (int k0 = 0; k0 < K; k0 += 32) {
        __syncthreads();
        __builtin_amdgcn_global_load_lds((const AS1 void*)(Ag0 + k0), (AS3 void*)la0, 16, 0, 0);
        __builtin_amdgcn_global_load_lds((const AS1 void*)(Ag1 + k0), (AS3 void*)la1, 16, 0, 0);
        __builtin_amdgcn_global_load_lds((const AS1 void*)(Bg0 + k0), (AS3 void*)lb0, 16, 0, 0);
        __builtin_amdgcn_global_load_lds((const AS1 void*)(Bg1 + k0), (AS3 void*)lb1, 16, 0, 0);
        __syncthreads();

        bf16x8_t af[4], bfr[4];
#pragma unroll
        for (int i = 0; i < 4; ++i)
            af[i] = *(const bf16x8_t*)&As[(wm + i * 16 + fr) * 32 + fk];
#pragma unroll
        for (int j = 0; j < 4; ++j)
            bfr[j] = *(const bf16x8_t*)&Bs[(wn + j * 16 + fr) * 32 + fk];
#pragma unroll
        for (int i = 0; i < 4; ++i)
#pragma unroll
            for (int j = 0; j < 4; ++j)
                acc[i][j] = __builtin_amdgcn_mfma_f32_16x16x32_bf16(
                    af[i], bfr[j], acc[i][j], 0, 0, 0);
    }

    const int erow = (lane >> 4) * 4;
    const int ecol = lane & 15;
#pragma unroll
    for (int i = 0; i < 4; ++i) {
        int gr0 = bm + wm + i * 16 + erow;
#pragma unroll
        for (int j = 0; j < 4; ++j) {
            int gc = bn + wn + j * 16 + ecol;
#pragma unroll
            for (int r = 0; r < 4; ++r) {
                float v = acc[i][j][r];
                if (act == 1) {
                    float t = v + bias[gr0 + r];
                    v = (t > 20.f) ? t : log1pf(__expf(t));
                } else if (act == 2) {
                    v = v / (1.f + __expf(-v));
                }
                C[(size_t)(gr0 + r) * ldc + gc] = v;
            }
        }
    }
}

// ---------------------------------------------------------------------------
// causal depthwise conv (k=4) + bias + silu on [d][m] layout, bf16 output.
// ---------------------------------------------------------------------------
__global__ __launch_bounds__(256) void conv_silu_kernel(
    const float* __restrict__ xT,     // [2048][8192] fp32
    const float* __restrict__ w,      // [2048][4]
    const float* __restrict__ bias,   // [2048]
    unsigned short* __restrict__ xcT16) // [2048][8192] bf16
{
    int gid = blockIdx.x * blockDim.x + threadIdx.x;  // 0 .. 2048*2048-1
    int d = gid >> 11;
    int c4 = gid & 2047;
    int m0 = c4 * 4;
    int l0 = m0 & (L_SEQ - 1);

    const float* row = xT + (size_t)d * BL;
    float4 v = *(const float4*)(row + m0);
    float4 p;
    if (l0 == 0) { p.x = p.y = p.z = p.w = 0.f; }
    else         { p = *(const float4*)(row + m0 - 4); }

    float4 wv = ((const float4*)w)[d];
    float bb = bias[d];
    float e[4];
    e[0] = bb + wv.x * p.y + wv.y * p.z + wv.z * p.w + wv.w * v.x;
    e[1] = bb + wv.x * p.z + wv.y * p.w + wv.z * v.x + wv.w * v.y;
    e[2] = bb + wv.x * p.w + wv.y * v.x + wv.z * v.y + wv.w * v.z;
    e[3] = bb + wv.x * v.x + wv.y * v.y + wv.z * v.z + wv.w * v.w;
    ushort4 o;
    o.x = f2bf(e[0] / (1.f + __expf(-e[0])));
    o.y = f2bf(e[1] / (1.f + __expf(-e[1])));
    o.z = f2bf(e[2] / (1.f + __expf(-e[2])));
    o.w = f2bf(e[3] / (1.f + __expf(-e[3])));
    ((ushort4*)(xcT16 + (size_t)d * BL))[c4] = o;
}

// ---------------------------------------------------------------------------
// 32x32 tiled transposes (coalesced both sides)
// ---------------------------------------------------------------------------
__global__ __launch_bounds__(256) void transpose_f32_bf16(
    const float* __restrict__ in, int ldin,
    unsigned short* __restrict__ out, int ldout)
{
    __shared__ float tl[32][33];
    int r0 = blockIdx.y * 32, c0 = blockIdx.x * 32;
    int tx = threadIdx.x & 31, ty = threadIdx.x >> 5;
#pragma unroll
    for (int k = 0; k < 4; ++k)
        tl[ty + 8 * k][tx] = in[(size_t)(r0 + ty + 8 * k) * ldin + c0 + tx];
    __syncthreads();
#pragma unroll
    for (int k = 0; k < 4; ++k)
        out[(size_t)(c0 + ty + 8 * k) * ldout + r0 + tx] = f2bf(tl[tx][ty + 8 * k]);
}

__global__ __launch_bounds__(256) void transpose_bf16(
    const unsigned short* __restrict__ in, int ldin,
    unsigned short* __restrict__ out, int ldout)
{
    __shared__ unsigned short tl[32][33];
    int r0 = blockIdx.y * 32, c0 = blockIdx.x * 32;
    int tx = threadIdx.x & 31, ty = threadIdx.x >> 5;
#pragma unroll
    for (int k = 0; k < 4; ++k)
        tl[ty + 8 * k][tx] = in[(size_t)(r0 + ty + 8 * k) * ldin + c0 + tx];
    __syncthreads();
#pragma unroll
    for (int k = 0; k < 4; ++k)
        out[(size_t)(c0 + ty + 8 * k) * ldout + r0 + tx] = tl[tx][ty + 8 * k];
}

// ---------------------------------------------------------------------------
// Chunked parallel selective scan, DS-lean version.
// One block = one (b,d): 8 waves x 512-step chunks. lane = state n.
//   pass 1: per chunk (P,H) -> LDS      pass 2: compose -> h0
//   pass 3: groups of 8 steps: recurrence in regs, p[t][n] -> LDS once,
//           transpose-read reduction (2x ds_read_b128 + 3 shfl_xor per 8 steps)
// dt staged fp32, x staged bf16, broadcasts batched as b128 reads.
// B/C prefetched one group ahead (xdbl padded by 8 rows for tail prefetch).
// ---------------------------------------------------------------------------
#define SCAN_WAVES 8
#define CHUNK (L_SEQ / SCAN_WAVES)   // 512

__global__ __launch_bounds__(512, 4) void scan_kernel(
    const float* __restrict__ dtT,           // [2048][8192] fp32
    const unsigned short* __restrict__ xcT16,// [2048][8192] bf16
    const float* __restrict__ xdbl,          // [8192+8][256] fp32 (B@+128, C@+192)
    float* __restrict__ zyT,                 // [2048][8192]: silu(z) in, y out
    const float* __restrict__ A_log,         // [2048][64]
    const float* __restrict__ Dp)            // [2048]
{
    __shared__ __align__(16) float s_dt[L_SEQ];            // 16 KB
    __shared__ __align__(16) unsigned short s_x16[L_SEQ];  // 8 KB
    __shared__ float s_P[SCAN_WAVES][D_STATE];             // 2 KB
    __shared__ float s_H[SCAN_WAVES][D_STATE];             // 2 KB
    __shared__ __align__(16) float s_p[SCAN_WAVES][8][68]; // 17 KB
    // total ~45.4 KB -> 3 blocks/CU

    const int bd  = blockIdx.x;            // 0..4095
    const int b   = bd >> 11;
    const int d   = bd & (D_INNER - 1);
    const int tid = threadIdx.x;           // 0..511
    const int wid = tid >> 6;
    const int lane = tid & 63;

    const size_t rowbase = (size_t)d * BL + (size_t)b * L_SEQ;

    // stage dt (fp32, 1024 float4) and x (bf16, 1024 ushort4), fully coalesced
    ((float4*)s_dt)[tid]         = ((const float4*)(dtT + rowbase))[tid];
    ((float4*)s_dt)[tid + 512]   = ((const float4*)(dtT + rowbase))[tid + 512];
    ((ushort4*)s_x16)[tid]       = ((const ushort4*)(xcT16 + rowbase))[tid];
    ((ushort4*)s_x16)[tid + 512] = ((const ushort4*)(xcT16 + rowbase))[tid + 512];

    const float An = -__expf(A_log[d * D_STATE + lane]);
    const float Dd = Dp[d];
    __syncthreads();

    const int c0 = wid * CHUNK;
    const float* bcbase = xdbl + ((size_t)b * L_SEQ + c0) * 256 + DT_RANK + lane;

    // ---- pass 1: local chunk scan -> (P,H). Last chunk's result is unused.
    if (wid < SCAN_WAVES - 1) {
        float P = 1.f, H = 0.f;
        const float* bc = bcbase;
        float Bv[8];
#pragma unroll
        for (int t = 0; t < 8; ++t) Bv[t] = bc[t * 256];
        for (int g = 0; g < CHUNK; g += 8) {
            float Bn[8];
            const float* bn_ = bc + 8 * 256;
#pragma unroll
            for (int t = 0; t < 8; ++t) Bn[t] = bn_[t * 256];   // prefetch (pad-safe)
            float4 dta = *(const float4*)&s_dt[c0 + g];
            float4 dtb = *(const float4*)&s_dt[c0 + g + 4];
            uint4 xr = *(const uint4*)&s_x16[c0 + g];
            float dt8[8] = {dta.x, dta.y, dta.z, dta.w, dtb.x, dtb.y, dtb.z, dtb.w};
            float xf[8];
            xf[0] = __uint_as_float(xr.x << 16); xf[1] = __uint_as_float(xr.x & 0xffff0000u);
            xf[2] = __uint_as_float(xr.y << 16); xf[3] = __uint_as_float(xr.y & 0xffff0000u);
            xf[4] = __uint_as_float(xr.z << 16); xf[5] = __uint_as_float(xr.z & 0xffff0000u);
            xf[6] = __uint_as_float(xr.w << 16); xf[7] = __uint_as_float(xr.w & 0xffff0000u);
#pragma unroll
            for (int t = 0; t < 8; ++t) {
                float a = __expf(dt8[t] * An);
                H = fmaf(H, a, (dt8[t] * xf[t]) * Bv[t]);
                P *= a;
            }
#pragma unroll
            for (int t = 0; t < 8; ++t) Bv[t] = Bn[t];
            bc += 8 * 256;
        }
        s_P[wid][lane] = P;
        s_H[wid][lane] = H;
    }
    __syncthreads();

    // ---- pass 2: compose -> h0 for this chunk ----
    float h = 0.f;
    for (int c = 0; c < wid; ++c)
        h = fmaf(h, s_P[c][lane], s_H[c][lane]);

    // ---- pass 3: recurrence + transpose reduction, groups of 8 ----
    const int rt = lane & 7;          // reduction timestep
    const int ro = lane >> 3;         // reduction oct
    const float* prow = &s_p[wid][rt][ro * 8];
    float* zrow = zyT + rowbase + c0;

    const float* bc = bcbase;
    float Bv[8], Cv[8];
#pragma unroll
    for (int t = 0; t < 8; ++t) { Bv[t] = bc[t * 256]; Cv[t] = bc[t * 256 + D_STATE]; }

    for (int g = 0; g < CHUNK; g += 8) {
        float Bn[8], Cn[8];
        const float* bn_ = bc + 8 * 256;
#pragma unroll
        for (int t = 0; t < 8; ++t) {                     // prefetch next group
            Bn[t] = bn_[t * 256];
            Cn[t] = bn_[t * 256 + D_STATE];
        }

        float4 dta = *(const float4*)&s_dt[c0 + g];
        float4 dtb = *(const float4*)&s_dt[c0 + g + 4];
        uint4 xr = *(const uint4*)&s_x16[c0 + g];
        float dt8[8] = {dta.x, dta.y, dta.z, dta.w, dtb.x, dtb.y, dtb.z, dtb.w};
        float xf[8];
        xf[0] = __uint_as_float(xr.x << 16); xf[1] = __uint_as_float(xr.x & 0xffff0000u);
        xf[2] = __uint_as_float(xr.y << 16); xf[3] = __uint_as_float(xr.y & 0xffff0000u);
        xf[4] = __uint_as_float(xr.z << 16); xf[5] = __uint_as_float(xr.z & 0xffff0000u);
        xf[6] = __uint_as_float(xr.w << 16); xf[7] = __uint_as_float(xr.w & 0xffff0000u);

        float pr[8];
#pragma unroll
        for (int t = 0; t < 8; ++t) {
            float a = __expf(dt8[t] * An);
            h = fmaf(h, a, (dt8[t] * xf[t]) * Bv[t]);
            pr[t] = h * Cv[t];
        }
#pragma unroll
        for (int t = 0; t < 8; ++t) s_p[wid][t][lane] = pr[t];  // conflict-free

        // transpose-read reduction: lane (ro,rt) sums n in [8ro, 8ro+8) for step rt
        float4 q0 = *(const float4*)(prow);
        float4 q1 = *(const float4*)(prow + 4);
        float sum = ((q0.x + q0.y) + (q0.z + q0.w)) + ((q1.x + q1.y) + (q1.z + q1.w));
        sum += __shfl_xor(sum, 8);
        sum += __shfl_xor(sum, 16);
        sum += __shfl_xor(sum, 32);

        if (lane < 8) {   // lane == rt, ro == 0: has y for step g+lane
            float xv = bf2f(s_x16[c0 + g + lane]);
            float zv = zrow[g + lane];
            zrow[g + lane] = fmaf(Dd, xv, sum) * zv;
        }

#pragma unroll
        for (int t = 0; t < 8; ++t) { Bv[t] = Bn[t]; Cv[t] = Cn[t]; }
        bc += 8 * 256;
    }
}

// ---------------------------------------------------------------------------
extern "C" void kernel_launch(void* const* d_in, const int* in_sizes, int n_in,
                              void* d_out, int out_size, void* d_ws, size_t ws_size,
                              hipStream_t stream)
{
    const float* hs        = (const float*)d_in[0];  // [8192][1024]
    const float* in_proj_w = (const float*)d_in[1];  // [4096][1024]
    const float* conv_w    = (const float*)d_in[2];  // [2048][4]
    const float* conv_b    = (const float*)d_in[3];  // [2048]
    const float* x_proj_w  = (const float*)d_in[4];  // [256][2048]
    const float* dt_proj_w = (const float*)d_in[5];  // [2048][128]
    const float* dt_proj_b = (const float*)d_in[6];  // [2048]
    const float* A_log     = (const float*)d_in[7];  // [2048][64]
    const float* Dp        = (const float*)d_in[8];  // [2048]
    const float* out_proj_w= (const float*)d_in[9];  // [1024][2048]
    float* out = (float*)d_out;                      // [8192][1024]

    // workspace map (MiB offsets; peak ~177.5 MiB):
    //  S0 @0   : xT fp32 (64) -> xc16 bf16 (32) @0 -> dtT fp32 (64) @0
    //  S1 @64  : zT fp32 (64)  (scan writes y in place)
    //  S2 @128 : W1_16 (8)@128 + hs16 (16)@136 -> xcT16 bf16 (32)@128 -> y16 (32)@128
    //  tail    : xdbl fp32 (8+pad)@160, xdbl16 (2)@169, Wx16 (1)@171,
    //            Wdt16 (.5)@172, Wo16 (4)@173  (end 177)
    char* ws = (char*)d_ws;
    const size_t MiB = 1024 * 1024;
    float*          xT    = (float*)(ws);
    unsigned short* xc16  = (unsigned short*)(ws);
    float*          dtT   = (float*)(ws);
    float*          zT    = (float*)(ws + 64 * MiB);
    unsigned short* W1_16 = (unsigned short*)(ws + 128 * MiB);
    unsigned short* hs16  = (unsigned short*)(ws + 136 * MiB);
    unsigned short* xcT16 = (unsigned short*)(ws + 128 * MiB);
    unsigned short* y16   = (unsigned short*)(ws + 128 * MiB);
    float*          xdbl  = (float*)(ws + 160 * MiB);   // 8 MiB + 8-row pad
    unsigned short* xdbl16= (unsigned short*)(ws + 169 * MiB);
    unsigned short* Wx16  = (unsigned short*)(ws + 171 * MiB);
    unsigned short* Wdt16 = (unsigned short*)(ws + 172 * MiB);
    unsigned short* Wo16  = (unsigned short*)(ws + 173 * MiB);

    dim3 blk(256);

    // bf16 conversions
    cvt_f32_bf16<<<8192, blk, 0, stream>>>(hs, hs16, 2097152);
    cvt_f32_bf16<<<4096, blk, 0, stream>>>(in_proj_w, W1_16, 1048576);
    cvt_f32_bf16<<<512, blk, 0, stream>>>(x_proj_w, Wx16, 131072);
    cvt_f32_bf16<<<256, blk, 0, stream>>>(dt_proj_w, Wdt16, 65536);
    cvt_f32_bf16<<<2048, blk, 0, stream>>>(out_proj_w, Wo16, 524288);

    // 1) xT[d][m] = W1x . hs^T   (M=2048, N=8192, K=1024)
    gemm_bf16<<<dim3(64, 16), blk, 0, stream>>>(
        W1_16, D_MODEL, hs16, D_MODEL, xT, BL, D_MODEL, nullptr, 0);

    // 2) zT[d][m] = silu(W1z . hs^T)
    gemm_bf16<<<dim3(64, 16), blk, 0, stream>>>(
        W1_16 + (size_t)D_INNER * D_MODEL, D_MODEL, hs16, D_MODEL,
        zT, BL, D_MODEL, nullptr, 2);

    // 3) xcT16 = bf16(silu(conv(xT) + b))
    conv_silu_kernel<<<(D_INNER * (BL / 4)) / 256, blk, 0, stream>>>(
        xT, conv_w, conv_b, xcT16);

    // 4) xc16[m][d] = transpose(xcT16)
    transpose_bf16<<<dim3(BL / 32, D_INNER / 32), blk, 0, stream>>>(
        xcT16, BL, xc16, D_INNER);

    // 5) xdbl[m][256] = xc . x_proj^T   (M=8192, N=256, K=2048)
    gemm_bf16<<<dim3(2, 64), blk, 0, stream>>>(
        xc16, D_INNER, Wx16, D_INNER, xdbl, 256, D_INNER, nullptr, 0);

    // 6) xdbl16 = bf16(xdbl[:, :128])
    cvt_dtpart<<<1024, blk, 0, stream>>>(xdbl, xdbl16);

    // 7) dtT[d][m] = softplus(Wdt . xdbl_dt^T + b[d])  (M=2048, N=8192, K=128)
    gemm_bf16<<<dim3(64, 16), blk, 0, stream>>>(
        Wdt16, DT_RANK, xdbl16, DT_RANK, dtT, BL, DT_RANK, dt_proj_b, 1);

    // 8) chunked scan -> y in place over zT
    scan_kernel<<<B_SZ * D_INNER, dim3(512), 0, stream>>>(
        dtT, xcT16, xdbl, zT, A_log, Dp);

    // 9) y16[m][d] = bf16(transpose(zT))
    transpose_f32_bf16<<<dim3(BL / 32, D_INNER / 32), blk, 0, stream>>>(
        zT, BL, y16, D_INNER);

    // 10) out = y . out_proj^T   (M=8192, N=1024, K=2048)
    gemm_bf16<<<dim3(8, 64), blk, 0, stream>>>(
        y16, D_INNER, Wo16, D_INNER, out, D_MODEL, D_INNER, nullptr, 0);
}

// Round 8
// 1091.384 us; speedup vs baseline: 3.5313x; 1.0290x over previous
//
#include <hip/hip_runtime.h>
#include <math.h>

// Problem constants (fixed by the reference)
#define B_SZ 2
#define L_SEQ 4096
#define D_MODEL 1024
#define D_INNER 2048
#define D_STATE 64
#define DT_RANK 128
#define BL (B_SZ * L_SEQ)          // 8192 tokens

#define AS1 __attribute__((address_space(1)))
#define AS3 __attribute__((address_space(3)))

typedef __attribute__((ext_vector_type(8))) short bf16x8_t;  // 8 bf16 = 4 VGPRs
typedef __attribute__((ext_vector_type(4))) float f32x4_t;

__device__ __forceinline__ unsigned short f2bf(float f) {
    unsigned int u = __float_as_uint(f);
    u = (u + 0x7FFFu + ((u >> 16) & 1u)) >> 16;   // RNE
    return (unsigned short)u;
}
__device__ __forceinline__ float bf2f(unsigned short h) {
    return __uint_as_float(((unsigned int)h) << 16);
}

// ---------------------------------------------------------------------------
// fp32 -> bf16 bulk convert (n4 = count of float4 groups)
// ---------------------------------------------------------------------------
__global__ __launch_bounds__(256) void cvt_f32_bf16(
    const float* __restrict__ in, unsigned short* __restrict__ out, int n4)
{
    int i = blockIdx.x * 256 + threadIdx.x;
    if (i >= n4) return;
    float4 v = ((const float4*)in)[i];
    ushort4 o;
    o.x = f2bf(v.x); o.y = f2bf(v.y); o.z = f2bf(v.z); o.w = f2bf(v.w);
    ((ushort4*)out)[i] = o;
}

// xdbl[:, :128] (fp32, row stride 256) -> packed bf16 [8192][128]
__global__ __launch_bounds__(256) void cvt_dtpart(
    const float* __restrict__ xdbl, unsigned short* __restrict__ out)
{
    int i = blockIdx.x * 256 + threadIdx.x;   // 0 .. 8192*32-1
    int m = i >> 5, c = i & 31;
    float4 v = *(const float4*)(xdbl + (size_t)m * 256 + c * 4);
    ushort4 o;
    o.x = f2bf(v.x); o.y = f2bf(v.y); o.z = f2bf(v.z); o.w = f2bf(v.w);
    ((ushort4*)(out))[(size_t)m * 32 + c] = o;
}

// ---------------------------------------------------------------------------
// bf16 MFMA GEMM: C[m][n] = act( sum_k A[m][k]*B[n][k] [+ bias[m]] )
// A: M x K bf16 row-major (lda), B: N x K bf16 row-major (ldb), C fp32 (ldc).
// act: 0 none, 1 softplus with bias indexed by ROW m, 2 silu.
// Tile 128x128, BK=32, 256 threads = 4 waves (2x2 of 64x64 per wave).
// ---------------------------------------------------------------------------
__global__ __launch_bounds__(256) void gemm_bf16(
    const unsigned short* __restrict__ A, int lda,
    const unsigned short* __restrict__ B, int ldb,
    float* __restrict__ C, int ldc, int K,
    const float* __restrict__ bias, int act)
{
    __shared__ unsigned short As[128 * 32];   // [row][k] linear, no pad
    __shared__ unsigned short Bs[128 * 32];

    const int tid = threadIdx.x;
    const int w = tid >> 6, lane = tid & 63;
    const int bm = blockIdx.y * 128, bn = blockIdx.x * 128;
    const int wm = (w & 1) * 64, wn = (w >> 1) * 64;

    f32x4_t acc[4][4];
#pragma unroll
    for (int i = 0; i < 4; ++i)
#pragma unroll
        for (int j = 0; j < 4; ++j) acc[i][j] = (f32x4_t){0.f, 0.f, 0.f, 0.f};

    const int srow = lane >> 2;
    const int scol = (lane & 3) * 8;
    const unsigned short* Ag0 = A + (size_t)(bm + w * 16 + srow) * lda + scol;
    const unsigned short* Ag1 = A + (size_t)(bm + 64 + w * 16 + srow) * lda + scol;
    const unsigned short* Bg0 = B + (size_t)(bn + w * 16 + srow) * ldb + scol;
    const unsigned short* Bg1 = B + (size_t)(bn + 64 + w * 16 + srow) * ldb + scol;
    unsigned short* la0 = &As[(w * 16) * 32];
    unsigned short* la1 = &As[(64 + w * 16) * 32];
    unsigned short* lb0 = &Bs[(w * 16) * 32];
    unsigned short* lb1 = &Bs[(64 + w * 16) * 32];

    const int fr = lane & 15;
    const int fk = (lane >> 4) * 8;

    for (int k0 = 0; k0 < K; k0 += 32) {
        __syncthreads();
        __builtin_amdgcn_global_load_lds((const AS1 void*)(Ag0 + k0), (AS3 void*)la0, 16, 0, 0);
        __builtin_amdgcn_global_load_lds((const AS1 void*)(Ag1 + k0), (AS3 void*)la1, 16, 0, 0);
        __builtin_amdgcn_global_load_lds((const AS1 void*)(Bg0 + k0), (AS3 void*)lb0, 16, 0, 0);
        __builtin_amdgcn_global_load_lds((const AS1 void*)(Bg1 + k0), (AS3 void*)lb1, 16, 0, 0);
        __syncthreads();

        bf16x8_t af[4], bfr[4];
#pragma unroll
        for (int i = 0; i < 4; ++i)
            af[i] = *(const bf16x8_t*)&As[(wm + i * 16 + fr) * 32 + fk];
#pragma unroll
        for (int j = 0; j < 4; ++j)
            bfr[j] = *(const bf16x8_t*)&Bs[(wn + j * 16 + fr) * 32 + fk];
#pragma unroll
        for (int i = 0; i < 4; ++i)
#pragma unroll
            for (int j = 0; j < 4; ++j)
                acc[i][j] = __builtin_amdgcn_mfma_f32_16x16x32_bf16(
                    af[i], bfr[j], acc[i][j], 0, 0, 0);
    }

    const int erow = (lane >> 4) * 4;
    const int ecol = lane & 15;
#pragma unroll
    for (int i = 0; i < 4; ++i) {
        int gr0 = bm + wm + i * 16 + erow;
#pragma unroll
        for (int j = 0; j < 4; ++j) {
            int gc = bn + wn + j * 16 + ecol;
#pragma unroll
            for (int r = 0; r < 4; ++r) {
                float v = acc[i][j][r];
                if (act == 1) {
                    float t = v + bias[gr0 + r];
                    v = (t > 20.f) ? t : log1pf(__expf(t));
                } else if (act == 2) {
                    v = v / (1.f + __expf(-v));
                }
                C[(size_t)(gr0 + r) * ldc + gc] = v;
            }
        }
    }
}

// ---------------------------------------------------------------------------
// causal depthwise conv (k=4) + bias + silu on [d][m] layout, bf16 output.
// ---------------------------------------------------------------------------
__global__ __launch_bounds__(256) void conv_silu_kernel(
    const float* __restrict__ xT,     // [2048][8192] fp32
    const float* __restrict__ w,      // [2048][4]
    const float* __restrict__ bias,   // [2048]
    unsigned short* __restrict__ xcT16) // [2048][8192] bf16
{
    int gid = blockIdx.x * blockDim.x + threadIdx.x;  // 0 .. 2048*2048-1
    int d = gid >> 11;
    int c4 = gid & 2047;
    int m0 = c4 * 4;
    int l0 = m0 & (L_SEQ - 1);

    const float* row = xT + (size_t)d * BL;
    float4 v = *(const float4*)(row + m0);
    float4 p;
    if (l0 == 0) { p.x = p.y = p.z = p.w = 0.f; }
    else         { p = *(const float4*)(row + m0 - 4); }

    float4 wv = ((const float4*)w)[d];
    float bb = bias[d];
    float e[4];
    e[0] = bb + wv.x * p.y + wv.y * p.z + wv.z * p.w + wv.w * v.x;
    e[1] = bb + wv.x * p.z + wv.y * p.w + wv.z * v.x + wv.w * v.y;
    e[2] = bb + wv.x * p.w + wv.y * v.x + wv.z * v.y + wv.w * v.z;
    e[3] = bb + wv.x * v.x + wv.y * v.y + wv.z * v.z + wv.w * v.w;
    ushort4 o;
    o.x = f2bf(e[0] / (1.f + __expf(-e[0])));
    o.y = f2bf(e[1] / (1.f + __expf(-e[1])));
    o.z = f2bf(e[2] / (1.f + __expf(-e[2])));
    o.w = f2bf(e[3] / (1.f + __expf(-e[3])));
    ((ushort4*)(xcT16 + (size_t)d * BL))[c4] = o;
}

// ---------------------------------------------------------------------------
// 32x32 tiled transposes (coalesced both sides)
// ---------------------------------------------------------------------------
__global__ __launch_bounds__(256) void transpose_f32_bf16(
    const float* __restrict__ in, int ldin,
    unsigned short* __restrict__ out, int ldout)
{
    __shared__ float tl[32][33];
    int r0 = blockIdx.y * 32, c0 = blockIdx.x * 32;
    int tx = threadIdx.x & 31, ty = threadIdx.x >> 5;
#pragma unroll
    for (int k = 0; k < 4; ++k)
        tl[ty + 8 * k][tx] = in[(size_t)(r0 + ty + 8 * k) * ldin + c0 + tx];
    __syncthreads();
#pragma unroll
    for (int k = 0; k < 4; ++k)
        out[(size_t)(c0 + ty + 8 * k) * ldout + r0 + tx] = f2bf(tl[tx][ty + 8 * k]);
}

__global__ __launch_bounds__(256) void transpose_bf16(
    const unsigned short* __restrict__ in, int ldin,
    unsigned short* __restrict__ out, int ldout)
{
    __shared__ unsigned short tl[32][33];
    int r0 = blockIdx.y * 32, c0 = blockIdx.x * 32;
    int tx = threadIdx.x & 31, ty = threadIdx.x >> 5;
#pragma unroll
    for (int k = 0; k < 4; ++k)
        tl[ty + 8 * k][tx] = in[(size_t)(r0 + ty + 8 * k) * ldin + c0 + tx];
    __syncthreads();
#pragma unroll
    for (int k = 0; k < 4; ++k)
        out[(size_t)(c0 + ty + 8 * k) * ldout + r0 + tx] = tl[tx][ty + 8 * k];
}

// ---------------------------------------------------------------------------
// Chunked parallel selective scan, register-butterfly version.
// One block = one (b,d): 8 waves x 512-step chunks. lane = state n.
//   pass 1: per chunk (P,H) -> LDS      pass 2: compose -> h0
//   pass 3: groups of 8 steps: recurrence in regs; n-reduction via 3 fold
//           stages (xor 32/16/8, blended sends: 4+2+1 shfl) leaving lane L
//           with step t=(L>>3)&7 partial over n==L&7 (mod 8), then xor-4/2/1
//           butterfly. 10 shuffles / 8 steps, ZERO LDS for p.
// b = blockIdx&1 so each XCD's round-robin share reads one batch's xdbl (L2).
// ---------------------------------------------------------------------------
#define SCAN_WAVES 8
#define CHUNK (L_SEQ / SCAN_WAVES)   // 512

__global__ __launch_bounds__(512, 8) void scan_kernel(
    const float* __restrict__ dtT,           // [2048][8192] fp32
    const unsigned short* __restrict__ xcT16,// [2048][8192] bf16
    const float* __restrict__ xdbl,          // [8192+8][256] fp32 (B@+128, C@+192)
    float* __restrict__ zyT,                 // [2048][8192]: silu(z) in, y out
    const float* __restrict__ A_log,         // [2048][64]
    const float* __restrict__ Dp)            // [2048]
{
    __shared__ __align__(16) float s_dt[L_SEQ];            // 16 KB
    __shared__ __align__(16) unsigned short s_x16[L_SEQ];  // 8 KB
    __shared__ float s_P[SCAN_WAVES][D_STATE];             // 2 KB
    __shared__ float s_H[SCAN_WAVES][D_STATE];             // 2 KB
    // total ~28.3 KB -> 4 blocks/CU (32 waves = full occupancy)

    const int bd  = blockIdx.x;            // 0..4095
    const int b   = bd & 1;                // XCD-friendly: same-b per XCD
    const int d   = bd >> 1;
    const int tid = threadIdx.x;           // 0..511
    const int wid = tid >> 6;
    const int lane = tid & 63;

    const size_t rowbase = (size_t)d * BL + (size_t)b * L_SEQ;

    // stage dt (fp32, 1024 float4) and x (bf16, 1024 ushort4), fully coalesced
    ((float4*)s_dt)[tid]         = ((const float4*)(dtT + rowbase))[tid];
    ((float4*)s_dt)[tid + 512]   = ((const float4*)(dtT + rowbase))[tid + 512];
    ((ushort4*)s_x16)[tid]       = ((const ushort4*)(xcT16 + rowbase))[tid];
    ((ushort4*)s_x16)[tid + 512] = ((const ushort4*)(xcT16 + rowbase))[tid + 512];

    const float An = -__expf(A_log[d * D_STATE + lane]);
    const float Dd = Dp[d];
    __syncthreads();

    const int c0 = wid * CHUNK;
    const float* bcbase = xdbl + ((size_t)b * L_SEQ + c0) * 256 + DT_RANK + lane;

    // ---- pass 1: local chunk scan -> (P,H). Last chunk's result is unused.
    if (wid < SCAN_WAVES - 1) {
        float P = 1.f, H = 0.f;
        const float* bc = bcbase;
        float Bv[8];
#pragma unroll
        for (int t = 0; t < 8; ++t) Bv[t] = bc[t * 256];
        for (int g = 0; g < CHUNK; g += 8) {
            float Bn[8];
            const float* bn_ = bc + 8 * 256;
#pragma unroll
            for (int t = 0; t < 8; ++t) Bn[t] = bn_[t * 256];   // prefetch (pad-safe)
            float4 dta = *(const float4*)&s_dt[c0 + g];
            float4 dtb = *(const float4*)&s_dt[c0 + g + 4];
            uint4 xr = *(const uint4*)&s_x16[c0 + g];
            float dt8[8] = {dta.x, dta.y, dta.z, dta.w, dtb.x, dtb.y, dtb.z, dtb.w};
            float xf[8];
            xf[0] = __uint_as_float(xr.x << 16); xf[1] = __uint_as_float(xr.x & 0xffff0000u);
            xf[2] = __uint_as_float(xr.y << 16); xf[3] = __uint_as_float(xr.y & 0xffff0000u);
            xf[4] = __uint_as_float(xr.z << 16); xf[5] = __uint_as_float(xr.z & 0xffff0000u);
            xf[6] = __uint_as_float(xr.w << 16); xf[7] = __uint_as_float(xr.w & 0xffff0000u);
#pragma unroll
            for (int t = 0; t < 8; ++t) {
                float a = __expf(dt8[t] * An);
                H = fmaf(H, a, (dt8[t] * xf[t]) * Bv[t]);
                P *= a;
            }
#pragma unroll
            for (int t = 0; t < 8; ++t) Bv[t] = Bn[t];
            bc += 8 * 256;
        }
        s_P[wid][lane] = P;
        s_H[wid][lane] = H;
    }
    __syncthreads();

    // ---- pass 2: compose -> h0 for this chunk ----
    float h = 0.f;
    for (int c = 0; c < wid; ++c)
        h = fmaf(h, s_P[c][lane], s_H[c][lane]);

    // ---- pass 3: recurrence + register fold-butterfly reduction ----
    float* zrow = zyT + rowbase + c0;
    const int myt = (lane >> 3) & 7;       // step index this lane ends up with

    const float* bc = bcbase;
    float Bv[8], Cv[8];
#pragma unroll
    for (int t = 0; t < 8; ++t) { Bv[t] = bc[t * 256]; Cv[t] = bc[t * 256 + D_STATE]; }

    for (int g = 0; g < CHUNK; g += 8) {
        float Bn[8], Cn[8];
        const float* bn_ = bc + 8 * 256;
#pragma unroll
        for (int t = 0; t < 8; ++t) {                     // prefetch next group
            Bn[t] = bn_[t * 256];
            Cn[t] = bn_[t * 256 + D_STATE];
        }

        float4 dta = *(const float4*)&s_dt[c0 + g];
        float4 dtb = *(const float4*)&s_dt[c0 + g + 4];
        uint4 xr = *(const uint4*)&s_x16[c0 + g];
        float dt8[8] = {dta.x, dta.y, dta.z, dta.w, dtb.x, dtb.y, dtb.z, dtb.w};
        float xf[8];
        xf[0] = __uint_as_float(xr.x << 16); xf[1] = __uint_as_float(xr.x & 0xffff0000u);
        xf[2] = __uint_as_float(xr.y << 16); xf[3] = __uint_as_float(xr.y & 0xffff0000u);
        xf[4] = __uint_as_float(xr.z << 16); xf[5] = __uint_as_float(xr.z & 0xffff0000u);
        xf[6] = __uint_as_float(xr.w << 16); xf[7] = __uint_as_float(xr.w & 0xffff0000u);

        float pr[8];
#pragma unroll
        for (int t = 0; t < 8; ++t) {
            float a = __expf(dt8[t] * An);
            h = fmaf(h, a, (dt8[t] * xf[t]) * Bv[t]);
            pr[t] = h * Cv[t];
        }

        // fold stage 1 (xor 32): 8 values -> 4
#pragma unroll
        for (int t = 0; t < 4; ++t) {
            float send = (lane & 32) ? pr[t] : pr[t + 4];
            float recv = __shfl_xor(send, 32);
            pr[t] = ((lane & 32) ? pr[t + 4] : pr[t]) + recv;
        }
        // fold stage 2 (xor 16): 4 -> 2
#pragma unroll
        for (int t = 0; t < 2; ++t) {
            float send = (lane & 16) ? pr[t] : pr[t + 2];
            float recv = __shfl_xor(send, 16);
            pr[t] = ((lane & 16) ? pr[t + 2] : pr[t]) + recv;
        }
        // fold stage 3 (xor 8): 2 -> 1  (lane now holds step myt, n==lane&7 mod 8)
        {
            float send = (lane & 8) ? pr[0] : pr[1];
            float recv = __shfl_xor(send, 8);
            pr[0] = ((lane & 8) ? pr[1] : pr[0]) + recv;
        }
        // butterfly over the 8 n-residues
        pr[0] += __shfl_xor(pr[0], 4);
        pr[0] += __shfl_xor(pr[0], 2);
        pr[0] += __shfl_xor(pr[0], 1);

        if ((lane & 7) == 0) {   // one lane per step group
            float xv = bf2f(s_x16[c0 + g + myt]);
            float zv = zrow[g + myt];
            zrow[g + myt] = fmaf(Dd, xv, pr[0]) * zv;
        }

#pragma unroll
        for (int t = 0; t < 8; ++t) { Bv[t] = Bn[t]; Cv[t] = Cn[t]; }
        bc += 8 * 256;
    }
}

// ---------------------------------------------------------------------------
extern "C" void kernel_launch(void* const* d_in, const int* in_sizes, int n_in,
                              void* d_out, int out_size, void* d_ws, size_t ws_size,
                              hipStream_t stream)
{
    const float* hs        = (const float*)d_in[0];  // [8192][1024]
    const float* in_proj_w = (const float*)d_in[1];  // [4096][1024]
    const float* conv_w    = (const float*)d_in[2];  // [2048][4]
    const float* conv_b    = (const float*)d_in[3];  // [2048]
    const float* x_proj_w  = (const float*)d_in[4];  // [256][2048]
    const float* dt_proj_w = (const float*)d_in[5];  // [2048][128]
    const float* dt_proj_b = (const float*)d_in[6];  // [2048]
    const float* A_log     = (const float*)d_in[7];  // [2048][64]
    const float* Dp        = (const float*)d_in[8];  // [2048]
    const float* out_proj_w= (const float*)d_in[9];  // [1024][2048]
    float* out = (float*)d_out;                      // [8192][1024]

    // workspace map (MiB offsets; peak ~177.5 MiB):
    //  S0 @0   : xT fp32 (64) -> xc16 bf16 (32) @0 -> dtT fp32 (64) @0
    //  S1 @64  : zT fp32 (64)  (scan writes y in place)
    //  S2 @128 : W1_16 (8)@128 + hs16 (16)@136 -> xcT16 bf16 (32)@128 -> y16 (32)@128
    //  tail    : xdbl fp32 (8+pad)@160, xdbl16 (2)@169, Wx16 (1)@171,
    //            Wdt16 (.5)@172, Wo16 (4)@173  (end 177)
    char* ws = (char*)d_ws;
    const size_t MiB = 1024 * 1024;
    float*          xT    = (float*)(ws);
    unsigned short* xc16  = (unsigned short*)(ws);
    float*          dtT   = (float*)(ws);
    float*          zT    = (float*)(ws + 64 * MiB);
    unsigned short* W1_16 = (unsigned short*)(ws + 128 * MiB);
    unsigned short* hs16  = (unsigned short*)(ws + 136 * MiB);
    unsigned short* xcT16 = (unsigned short*)(ws + 128 * MiB);
    unsigned short* y16   = (unsigned short*)(ws + 128 * MiB);
    float*          xdbl  = (float*)(ws + 160 * MiB);   // 8 MiB + 8-row pad
    unsigned short* xdbl16= (unsigned short*)(ws + 169 * MiB);
    unsigned short* Wx16  = (unsigned short*)(ws + 171 * MiB);
    unsigned short* Wdt16 = (unsigned short*)(ws + 172 * MiB);
    unsigned short* Wo16  = (unsigned short*)(ws + 173 * MiB);

    dim3 blk(256);

    // bf16 conversions
    cvt_f32_bf16<<<8192, blk, 0, stream>>>(hs, hs16, 2097152);
    cvt_f32_bf16<<<4096, blk, 0, stream>>>(in_proj_w, W1_16, 1048576);
    cvt_f32_bf16<<<512, blk, 0, stream>>>(x_proj_w, Wx16, 131072);
    cvt_f32_bf16<<<256, blk, 0, stream>>>(dt_proj_w, Wdt16, 65536);
    cvt_f32_bf16<<<2048, blk, 0, stream>>>(out_proj_w, Wo16, 524288);

    // 1) xT[d][m] = W1x . hs^T   (M=2048, N=8192, K=1024)
    gemm_bf16<<<dim3(64, 16), blk, 0, stream>>>(
        W1_16, D_MODEL, hs16, D_MODEL, xT, BL, D_MODEL, nullptr, 0);

    // 2) zT[d][m] = silu(W1z . hs^T)
    gemm_bf16<<<dim3(64, 16), blk, 0, stream>>>(
        W1_16 + (size_t)D_INNER * D_MODEL, D_MODEL, hs16, D_MODEL,
        zT, BL, D_MODEL, nullptr, 2);

    // 3) xcT16 = bf16(silu(conv(xT) + b))
    conv_silu_kernel<<<(D_INNER * (BL / 4)) / 256, blk, 0, stream>>>(
        xT, conv_w, conv_b, xcT16);

    // 4) xc16[m][d] = transpose(xcT16)
    transpose_bf16<<<dim3(BL / 32, D_INNER / 32), blk, 0, stream>>>(
        xcT16, BL, xc16, D_INNER);

    // 5) xdbl[m][256] = xc . x_proj^T   (M=8192, N=256, K=2048)
    gemm_bf16<<<dim3(2, 64), blk, 0, stream>>>(
        xc16, D_INNER, Wx16, D_INNER, xdbl, 256, D_INNER, nullptr, 0);

    // 6) xdbl16 = bf16(xdbl[:, :128])
    cvt_dtpart<<<1024, blk, 0, stream>>>(xdbl, xdbl16);

    // 7) dtT[d][m] = softplus(Wdt . xdbl_dt^T + b[d])  (M=2048, N=8192, K=128)
    gemm_bf16<<<dim3(64, 16), blk, 0, stream>>>(
        Wdt16, DT_RANK, xdbl16, DT_RANK, dtT, BL, DT_RANK, dt_proj_b, 1);

    // 8) chunked scan -> y in place over zT
    scan_kernel<<<B_SZ * D_INNER, dim3(512), 0, stream>>>(
        dtT, xcT16, xdbl, zT, A_log, Dp);

    // 9) y16[m][d] = bf16(transpose(zT))
    transpose_f32_bf16<<<dim3(BL / 32, D_INNER / 32), blk, 0, stream>>>(
        zT, BL, y16, D_INNER);

    // 10) out = y . out_proj^T   (M=8192, N=1024, K=2048)
    gemm_bf16<<<dim3(8, 64), blk, 0, stream>>>(
        y16, D_INNER, Wo16, D_INNER, out, D_MODEL, D_INNER, nullptr, 0);
}